// Round 3
// baseline (239.828 us; speedup 1.0000x reference)
//
#include <hip/hip_runtime.h>

typedef _Float16 f16;
typedef __attribute__((ext_vector_type(4))) _Float16 f16x4;
typedef __attribute__((ext_vector_type(8))) _Float16 f16x8;
typedef __attribute__((ext_vector_type(4))) float f32x4;

#define NB 2
#define NS 2048
#define NHID 2048
#define N_H 16
#define N_KV 4
#define N_HD 128

__device__ __forceinline__ void gload16(void* lds, const void* g) {
  __builtin_amdgcn_global_load_lds(
      (const __attribute__((address_space(1))) unsigned int*)g,
      (__attribute__((address_space(3))) unsigned int*)lds, 16, 0, 0);
}

// ---------------- f32 -> f16 convert (vectorized) ----------------
__global__ __launch_bounds__(256) void cvt_kernel(const float* __restrict__ in,
                                                  f16* __restrict__ out, int n4) {
  int i = blockIdx.x * 256 + threadIdx.x;
  if (i >= n4) return;
  const float4 v = reinterpret_cast<const float4*>(in)[i];
  f16x4 o = {(f16)v.x, (f16)v.y, (f16)v.z, (f16)v.w};
  reinterpret_cast<f16x4*>(out)[i] = o;
}

// 3-source convert into one contiguous dest (Wq|Wk|Wv)
__global__ __launch_bounds__(256) void cvt3_kernel(const float* __restrict__ a, int na4,
                                                   const float* __restrict__ b, int nb4,
                                                   const float* __restrict__ c, int nc4,
                                                   f16* __restrict__ out) {
  int i = blockIdx.x * 256 + threadIdx.x;
  if (i >= na4 + nb4 + nc4) return;
  const float* src;
  int j;
  if (i < na4) { src = a; j = i; }
  else if (i < na4 + nb4) { src = b; j = i - na4; }
  else { src = c; j = i - na4 - nb4; }
  const float4 v = reinterpret_cast<const float4*>(src)[j];
  f16x4 o = {(f16)v.x, (f16)v.y, (f16)v.z, (f16)v.w};
  reinterpret_cast<f16x4*>(out)[i] = o;
}

// ---------------- pipelined GEMM: C[M,N] = A[M,K] * B[N,K]^T ----------------
// BN=256 fixed, BM = MREP*32 (256 or 128). 8 waves (2Mx4N), BK=32.
// 4 LDS buffers (ring); stage tile kt+3 while computing kt; counted vmcnt
// (2G outstanding = 2 tiles in flight), never 0 in steady state.
// LDS granule layout L(r,c16) = (r>>3)*512B + c16*128B + (r&7)*16B  ->
// frag ds_read_b128 down 16 rows hits 8 distinct 16B slots x2 (conflict-free);
// staging keeps LDS linear and permutes the per-lane GLOBAL source (m173).
// MODE 0: scatter into Q/K/V fp16 [B,H,S,D].  MODE 1: f32 out + bias.
template <int MREP, int MODE>
__global__ __launch_bounds__(512, 2) void gemm8(
    const f16* __restrict__ A, const f16* __restrict__ Bm, const int K,
    f16* __restrict__ q_out, f16* __restrict__ k_out, f16* __restrict__ v_out,
    float* __restrict__ f_out, const float* __restrict__ bias) {
  constexpr int BM = MREP * 32;            // 256 or 128
  constexpr int GA = BM / 128;             // A granules (8KB each): 2 or 1
  constexpr int G = GA + 2;                // granules per K-tile
  constexpr int NPH = (MREP == 8) ? 2 : 1; // phases per K-tile
  constexpr int ATILE = BM * 32;           // f16 per A tile
  constexpr int BTILE = 256 * 32;
  constexpr int BUF = ATILE + BTILE;
  __shared__ f16 lds[4 * BUF];

  const int t = threadIdx.x;
  const int l = t & 63, w = t >> 6;
  const int g = l >> 4, l15 = l & 15;
  const int wr = w >> 2, wc = w & 3;  // 2 x 4 wave grid
  const int nb = blockIdx.x, mb = blockIdx.y;
  const int NT = K >> 5;

  const f16* Aorig = A + (size_t)(mb * BM) * K;
  const f16* Borig = Bm + (size_t)(nb * 256) * K;

  // precompute per-thread staging source offsets (f16 units) per granule
  size_t offA[GA], offB[2];
#pragma unroll
  for (int gi = 0; gi < GA; ++gi) {
    int beta = gi * 8192 + t * 16;
    int r = ((beta >> 9) << 3) | ((beta >> 4) & 7);
    int c = (beta >> 7) & 3;
    offA[gi] = (size_t)r * K + c * 8;
  }
#pragma unroll
  for (int gj = 0; gj < 2; ++gj) {
    int beta = gj * 8192 + t * 16;
    int r = ((beta >> 9) << 3) | ((beta >> 4) & 7);
    int c = (beta >> 7) & 3;
    offB[gj] = (size_t)r * K + c * 8;
  }

  auto stage = [&](int kt, int gi) {
    f16* bufbase = lds + (kt & 3) * BUF;
    if (gi < GA) {
      gload16(bufbase + gi * 4096 + w * 512, Aorig + offA[gi] + kt * 32);
    } else {
      int gj = gi - GA;
      gload16(bufbase + ATILE + gj * 4096 + w * 512, Borig + offB[gj] + kt * 32);
    }
  };
  // frag read offsets: idx = R0*32 + (l15>>3)*256 + g*64 + (l15&7)*8
  const int fragoff = ((l15 >> 3) << 8) + (g << 6) + ((l15 & 7) << 3);
  auto readA = [&](int kt, int mi) -> f16x8 {
    int R0 = wr * (MREP * 16) + mi * 16;
    return *reinterpret_cast<const f16x8*>(lds + (kt & 3) * BUF + R0 * 32 + fragoff);
  };
  auto readB = [&](int kt, int ni) -> f16x8 {
    int R0 = wc * 64 + ni * 16;
    return *reinterpret_cast<const f16x8*>(lds + (kt & 3) * BUF + ATILE + R0 * 32 + fragoff);
  };

  f32x4 acc[MREP][4] = {};

  // prologue: stage tiles 0,1,2; wait tile 0 (allow 2 in flight)
#pragma unroll
  for (int pt = 0; pt < 3; ++pt)
#pragma unroll
    for (int gi = 0; gi < G; ++gi) stage(pt, gi);
  if constexpr (MREP == 8) asm volatile("s_waitcnt vmcnt(8)" ::: "memory");
  else                     asm volatile("s_waitcnt vmcnt(6)" ::: "memory");
  __builtin_amdgcn_s_barrier();

  f16x8 bf[4];
  for (int kt = 0; kt < NT; ++kt) {
    const bool dostage = (kt + 3 < NT);
#pragma unroll
    for (int ph = 0; ph < NPH; ++ph) {
      f16x8 af[4];
#pragma unroll
      for (int mi = 0; mi < 4; ++mi) af[mi] = readA(kt, ph * 4 + mi);
      if (ph == 0) {
#pragma unroll
        for (int ni = 0; ni < 4; ++ni) bf[ni] = readB(kt, ni);
      }
      if (dostage) {
        if constexpr (NPH == 2) {
          stage(kt + 3, ph * 2);
          stage(kt + 3, ph * 2 + 1);
        } else {
          stage(kt + 3, 0);
          stage(kt + 3, 1);
          stage(kt + 3, 2);
        }
      }
      if (ph == NPH - 1) {
        // gate tile kt+1: allow stagings of tiles kt+2, kt+3 to remain in flight
        if (kt + 3 < NT) {
          if constexpr (MREP == 8) asm volatile("s_waitcnt vmcnt(8)" ::: "memory");
          else                     asm volatile("s_waitcnt vmcnt(6)" ::: "memory");
        } else if (kt + 2 < NT) {
          if constexpr (MREP == 8) asm volatile("s_waitcnt vmcnt(4)" ::: "memory");
          else                     asm volatile("s_waitcnt vmcnt(3)" ::: "memory");
        } else if (kt + 1 < NT) {
          asm volatile("s_waitcnt vmcnt(0)" ::: "memory");
        }
      }
      __builtin_amdgcn_s_barrier();
      asm volatile("s_waitcnt lgkmcnt(0)" ::: "memory");
      __builtin_amdgcn_s_setprio(1);
#pragma unroll
      for (int mi = 0; mi < 4; ++mi)
#pragma unroll
        for (int ni = 0; ni < 4; ++ni)
          acc[ph * 4 + mi][ni] =
              __builtin_amdgcn_mfma_f32_16x16x32_f16(af[mi], bf[ni], acc[ph * 4 + mi][ni], 0, 0, 0);
      __builtin_amdgcn_s_setprio(0);
      __builtin_amdgcn_s_barrier();
    }
  }

  // epilogue: D[row = 4*g + r][col = l15] per 16x16 fragment
#pragma unroll
  for (int mi = 0; mi < MREP; ++mi) {
    int m0 = mb * BM + wr * (MREP * 16) + mi * 16 + 4 * g;
#pragma unroll
    for (int ni = 0; ni < 4; ++ni) {
      int n = nb * 256 + wc * 64 + ni * 16 + l15;
#pragma unroll
      for (int r = 0; r < 4; ++r) {
        int mm = m0 + r;
        float val = acc[mi][ni][r];
        if (MODE == 0) {
          int b = mm >> 11, s = mm & (NS - 1);
          if (n < 2048) {
            int h = n >> 7, d = n & 127;
            q_out[(((size_t)(b * N_H + h)) * NS + s) * N_HD + d] = (f16)val;
          } else if (n < 2560) {
            int n2 = n - 2048, kvh = n2 >> 7, d = n2 & 127;
            k_out[(((size_t)(b * N_KV + kvh)) * NS + s) * N_HD + d] = (f16)val;
          } else {
            int n3 = n - 2560, kvh = n3 >> 7, d = n3 & 127;
            v_out[(((size_t)(b * N_KV + kvh)) * NS + s) * N_HD + d] = (f16)val;
          }
        } else {
          f_out[(size_t)mm * NHID + n] = val + bias[n];
        }
      }
    }
  }
}

// ---------------- V transpose: [B*NKV][S][HD] -> [B*NKV][HD][S] ----------------
__global__ __launch_bounds__(256) void transpose_v(const f16* __restrict__ V,
                                                   f16* __restrict__ Vt) {
  __shared__ f16 tt[64][72];
  int s0 = blockIdx.x * 64, d0 = blockIdx.y * 64, bk = blockIdx.z;
  const f16* Vp = V + (size_t)bk * NS * N_HD;
  f16* Vtp = Vt + (size_t)bk * N_HD * NS;
  int tid = threadIdx.x;
#pragma unroll
  for (int it = 0; it < 2; ++it) {
    int c = it * 256 + tid;
    int sr = c >> 3, dc = (c & 7) * 8;
    f16x8 v = *reinterpret_cast<const f16x8*>(Vp + (size_t)(s0 + sr) * N_HD + d0 + dc);
#pragma unroll
    for (int j = 0; j < 8; ++j) tt[dc + j][sr] = v[j];
  }
  __syncthreads();
#pragma unroll
  for (int it = 0; it < 2; ++it) {
    int c = it * 256 + tid;
    int dr = c >> 3, sc = (c & 7) * 8;
    f16x8 o;
#pragma unroll
    for (int j = 0; j < 8; ++j) o[j] = tt[dr][sc + j];
    *reinterpret_cast<f16x8*>(Vtp + (size_t)(d0 + dr) * NS + s0 + sc) = o;
  }
}

// ---------------- causal GQA flash attention ----------------
// Paired q-tiles {pi, 31-pi} share one K/V staging; double-buffered,
// stage(kt+1) before compute(kt). Softmax in exp2 domain (log2e folded
// into Q); T13 defer-max (skip rescale when max growth <= 11.5); T5 setprio.
__device__ __forceinline__ void stage_kv(const f16* __restrict__ Kp,
                                         const f16* __restrict__ Vp,
                                         f16* Kl, f16* Vl, int kt, int w, int l) {
#pragma unroll
  for (int it = 0; it < 4; ++it) {
    int cb = (it * 4 + w) * 64;
    int c = cb + l;
    int krow = c >> 4, pch = c & 15;
    int sch = (pch & 8) | ((pch ^ krow) & 7);
    gload16(Kl + cb * 8, Kp + (size_t)(kt * 64 + krow) * N_HD + sch * 8);
  }
#pragma unroll
  for (int it = 0; it < 4; ++it) {
    int cb = (it * 4 + w) * 64;
    int c = cb + l;
    int drow = c >> 3, pch = c & 7;
    int sch = (pch ^ drow) & 7;
    gload16(Vl + cb * 8, Vp + (size_t)drow * NS + kt * 64 + sch * 8);
  }
}

__device__ __forceinline__ void attn_step(
    const f16x8* qf, f32x4* oacc, float* mrow, float* lrow, int q0, int kt,
    const f16* Kl, const f16* Vl, f16* Pw, int g, int l15, bool diag) {
  // S = Q K^T (Q pre-scaled by log2e): acc D[q=4g+r][kpos=l15+16nt]
  f32x4 sacc[4];
  __builtin_amdgcn_s_setprio(1);
#pragma unroll
  for (int nt = 0; nt < 4; ++nt) {
    f32x4 z = {0.f, 0.f, 0.f, 0.f};
#pragma unroll
    for (int ks = 0; ks < 4; ++ks) {
      int kr = nt * 16 + l15;
      int ch = ks * 4 + g;
      int sw = (ch & 8) | ((ch ^ kr) & 7);
      f16x8 kf = *reinterpret_cast<const f16x8*>(Kl + kr * 128 + sw * 8);
      z = __builtin_amdgcn_mfma_f32_16x16x32_f16(qf[ks], kf, z, 0, 0, 0);
    }
    sacc[nt] = z;
  }
  __builtin_amdgcn_s_setprio(0);

  // causal mask (diag tile) + wave-parallel online softmax, base-2 domain
  float p[4][4], mx[4];
  bool need = false;
#pragma unroll
  for (int r = 0; r < 4; ++r) {
    int qg = q0 + r;
    float m = -3.0e38f;
#pragma unroll
    for (int nt = 0; nt < 4; ++nt) {
      float sv = sacc[nt][r];
      if (diag) {
        int kg = kt * 64 + nt * 16 + l15;
        if (kg > qg) sv = -3.0e38f;
      }
      p[nt][r] = sv;
      m = fmaxf(m, sv);
    }
#pragma unroll
    for (int off = 8; off >= 1; off >>= 1) m = fmaxf(m, __shfl_xor(m, off));
    mx[r] = m;
    need = need || (m > mrow[r] + 11.5f);
  }
  if (__any(need)) {  // T13 defer-max: rescale pass only when max grew
#pragma unroll
    for (int r = 0; r < 4; ++r) {
      float m2 = fmaxf(mrow[r], mx[r]);
      float alpha = __builtin_amdgcn_exp2f(mrow[r] - m2);
      mrow[r] = m2;
      lrow[r] *= alpha;
#pragma unroll
      for (int dt = 0; dt < 8; ++dt) oacc[dt][r] *= alpha;
    }
  }
#pragma unroll
  for (int r = 0; r < 4; ++r) {
    float rs = 0.f;
#pragma unroll
    for (int nt = 0; nt < 4; ++nt) {
      float pv = __builtin_amdgcn_exp2f(p[nt][r] - mrow[r]);
      p[nt][r] = pv;
      rs += pv;
    }
#pragma unroll
    for (int off = 8; off >= 1; off >>= 1) rs += __shfl_xor(rs, off);
    lrow[r] += rs;
  }

  // P -> per-wave LDS (swizzled), then read back as A-op fragments
#pragma unroll
  for (int nt = 0; nt < 4; ++nt)
#pragma unroll
    for (int r = 0; r < 4; ++r) {
      int ql = 4 * g + r;
      int kp = nt * 16 + l15;
      int ch = kp >> 3;
      int idx = ql * 64 + (ch ^ (ql & 7)) * 8 + (kp & 7);
      Pw[idx] = (f16)p[nt][r];
    }
  asm volatile("s_waitcnt lgkmcnt(0)" ::: "memory");
  __builtin_amdgcn_sched_barrier(0);

  f16x8 pa[2];
#pragma unroll
  for (int ks2 = 0; ks2 < 2; ++ks2) {
    int ch = ks2 * 4 + g;
    pa[ks2] = *reinterpret_cast<const f16x8*>(&Pw[l15 * 64 + (ch ^ (l15 & 7)) * 8]);
  }
  // O += P V : B-op = V[k][d] from Vl[d][k]
  __builtin_amdgcn_s_setprio(1);
#pragma unroll
  for (int dt = 0; dt < 8; ++dt)
#pragma unroll
    for (int ks2 = 0; ks2 < 2; ++ks2) {
      int d = dt * 16 + l15;
      int ch = ks2 * 4 + g;
      f16x8 vf = *reinterpret_cast<const f16x8*>(Vl + d * 64 + (ch ^ (d & 7)) * 8);
      oacc[dt] = __builtin_amdgcn_mfma_f32_16x16x32_f16(pa[ks2], vf, oacc[dt], 0, 0, 0);
    }
  __builtin_amdgcn_s_setprio(0);
}

__global__ __launch_bounds__(256, 2) void attn_kernel(
    const f16* __restrict__ Q, const f16* __restrict__ K,
    const f16* __restrict__ Vt, f16* __restrict__ O) {
  __shared__ f16 Klds[2][64 * 128];   // [k][d], chunk-swizzled by (k&7)
  __shared__ f16 Vlds[2][128 * 64];   // [d][k], chunk-swizzled by (d&7)
  __shared__ f16 Plds[4][16 * 64];    // per-wave P, chunk-swizzled by (q&7)
  const int t = threadIdx.x, l = t & 63, w = t >> 6;
  const int g = l >> 4, l15 = l & 15;
  const int pi = blockIdx.x;          // 0..15
  const int qtA = pi, qtB = 31 - pi;
  const int bh = blockIdx.y;
  const int b = bh >> 4, h = bh & 15;
  const int kvh = h >> 2;
  const f16* Qp = Q + ((size_t)(b * N_H + h)) * NS * N_HD;
  const f16* Kp = K + ((size_t)(b * N_KV + kvh)) * NS * N_HD;
  const f16* Vp = Vt + ((size_t)(b * N_KV + kvh)) * N_HD * NS;

  // Q fragments in registers for both tiles, pre-scaled by log2(e)
  const f16 l2e = (f16)1.44269504f;
  f16x8 qfA[4], qfB[4];
  const int qrA = qtA * 64 + w * 16 + l15;
  const int qrB = qtB * 64 + w * 16 + l15;
#pragma unroll
  for (int ks = 0; ks < 4; ++ks) {
    qfA[ks] = *reinterpret_cast<const f16x8*>(Qp + (size_t)qrA * N_HD + ks * 32 + g * 8);
    qfB[ks] = *reinterpret_cast<const f16x8*>(Qp + (size_t)qrB * N_HD + ks * 32 + g * 8);
#pragma unroll
    for (int j = 0; j < 8; ++j) { qfA[ks][j] *= l2e; qfB[ks][j] *= l2e; }
  }

  f32x4 oA[8] = {}, oB[8] = {};
  float mA[4], lAr[4], mB[4], lBr[4];
#pragma unroll
  for (int r = 0; r < 4; ++r) {
    mA[r] = -3.0e38f; lAr[r] = 0.f;
    mB[r] = -3.0e38f; lBr[r] = 0.f;
  }
  const int q0A = qtA * 64 + w * 16 + 4 * g;
  const int q0B = qtB * 64 + w * 16 + 4 * g;

  const int nkt = qtB + 1;
  stage_kv(Kp, Vp, Klds[0], Vlds[0], 0, w, l);
  asm volatile("s_waitcnt vmcnt(0)" ::: "memory");
  __syncthreads();
  int cur = 0;
  for (int kt = 0; kt < nkt; ++kt) {
    if (kt + 1 < nkt)
      stage_kv(Kp, Vp, Klds[cur ^ 1], Vlds[cur ^ 1], kt + 1, w, l);
    attn_step(qfB, oB, mB, lBr, q0B, kt, Klds[cur], Vlds[cur], Plds[w], g, l15, kt == qtB);
    if (kt <= qtA)
      attn_step(qfA, oA, mA, lAr, q0A, kt, Klds[cur], Vlds[cur], Plds[w], g, l15, kt == qtA);
    asm volatile("s_waitcnt vmcnt(0)" ::: "memory");
    __syncthreads();
    cur ^= 1;
  }

  // normalize + write attn_out [B*S][NH*HD] fp16
#pragma unroll
  for (int r = 0; r < 4; ++r) {
    float invB = 1.0f / lBr[r];
    f16* orowB = O + (size_t)(b * NS + q0B + r) * NHID + h * N_HD;
#pragma unroll
    for (int dt = 0; dt < 8; ++dt) orowB[dt * 16 + l15] = (f16)(oB[dt][r] * invB);
    float invA = 1.0f / lAr[r];
    f16* orowA = O + (size_t)(b * NS + q0A + r) * NHID + h * N_HD;
#pragma unroll
    for (int dt = 0; dt < 8; ++dt) orowA[dt * 16 + l15] = (f16)(oA[dt][r] * invA);
  }
}

extern "C" void kernel_launch(void* const* d_in, const int* in_sizes, int n_in,
                              void* d_out, int out_size, void* d_ws, size_t ws_size,
                              hipStream_t stream) {
  const float* hs = (const float*)d_in[0];
  const float* Wq = (const float*)d_in[1];
  const float* Wk = (const float*)d_in[2];
  const float* Wv = (const float*)d_in[3];
  const float* Wo = (const float*)d_in[4];
  const float* bo = (const float*)d_in[5];
  float* out = (float*)d_out;

  char* ws = (char*)d_ws;
  // layout (bytes): X 16MB | Wqkv 12MB | Wo 8MB | Q 16MB | K 4MB | V 4MB | Vt 4MB  = 64MiB
  f16* Xh   = (f16*)(ws);
  f16* Wqkv = (f16*)(ws + 16777216);
  f16* Woh  = (f16*)(ws + 29360128);
  f16* Qb   = (f16*)(ws + 37748736);
  f16* Kb   = (f16*)(ws + 54525952);
  f16* Vb   = (f16*)(ws + 58720256);
  f16* Vtb  = (f16*)(ws + 62914560);
  f16* Ob   = Xh;  // X dead after QKV GEMM; reuse for attention output

  cvt_kernel<<<8192, 256, 0, stream>>>(hs, Xh, 2097152);
  cvt3_kernel<<<6144, 256, 0, stream>>>(Wq, 1048576, Wk, 262144, Wv, 262144, Wqkv);
  cvt_kernel<<<4096, 256, 0, stream>>>(Wo, Woh, 1048576);

  gemm8<8, 0><<<dim3(12, 16), 512, 0, stream>>>(Xh, Wqkv, 2048, Qb, Kb, Vb, nullptr, nullptr);
  transpose_v<<<dim3(32, 2, 8), 256, 0, stream>>>(Vb, Vtb);
  attn_kernel<<<dim3(16, 32), 256, 0, stream>>>(Qb, Kb, Vtb, Ob);
  gemm8<4, 1><<<dim3(8, 32), 512, 0, stream>>>(Ob, Woh, 2048, nullptr, nullptr, nullptr, out, bo);
}